// Round 6
// baseline (522.056 us; speedup 1.0000x reference)
//
#include <hip/hip_runtime.h>
#include <math.h>

#define DD 128
// packed row: [e(128) | b(128) | s(128)] fp16 = 768 B
#define PSTRIDE 384

typedef _Float16 half8 __attribute__((ext_vector_type(8)));
typedef float floatx4 __attribute__((ext_vector_type(4)));

__device__ __forceinline__ float g16_sum(float x) {
#pragma unroll
  for (int m = 8; m >= 1; m >>= 1) x += __shfl_xor(x, m, 64);
  return x;
}
__device__ __forceinline__ int wave_sum_i(int x) {
#pragma unroll
  for (int m = 32; m >= 1; m >>= 1) x += __shfl_xor(x, m, 64);
  return x;
}

// ---- layer-0 GEMM tile: A fp32 direct, W fp32 with in-register fp16 convert ----
// part 0: out *= norm_out[row] (folds DGL 'both' src-weight into Qe)
// part 1/2: in-register row-norm -> logmap0/l2 scale on accumulator + bias.
__device__ __forceinline__ void gemm0_tile(int part, int rb, const float* __restrict__ A,
                                           const float* __restrict__ Wf, const float* __restrict__ Bb,
                                           const float* __restrict__ norm_out,
                                           _Float16* __restrict__ Q, int N) {
  int t = threadIdx.x, lane = t & 63, w = t >> 6;
  int m = lane & 15, quad = lane >> 4, c0 = w * 32;
  int rbase = rb * 64;
  _Float16* Qo = Q + part * DD;
  half8 bf[2][4];
#pragma unroll
  for (int tj = 0; tj < 2; ++tj)
#pragma unroll
    for (int kk = 0; kk < 4; ++kk) {
      const float* wp = &Wf[(c0 + tj * 16 + m) * DD + kk * 32 + quad * 8];
      float4 w0 = *(const float4*)wp;
      float4 w1 = *(const float4*)(wp + 4);
      half8 hv;
      hv[0] = (_Float16)w0.x; hv[1] = (_Float16)w0.y; hv[2] = (_Float16)w0.z; hv[3] = (_Float16)w0.w;
      hv[4] = (_Float16)w1.x; hv[5] = (_Float16)w1.y; hv[6] = (_Float16)w1.z; hv[7] = (_Float16)w1.w;
      bf[tj][kk] = hv;
    }
  float bias0 = 0.f, bias1 = 0.f;
  if (part) { bias0 = Bb[c0 + m]; bias1 = Bb[c0 + 16 + m]; }
#pragma unroll
  for (int r = 0; r < 4; ++r) {
    int row0 = r * 16;
    int arow = rbase + row0 + m; if (arow >= N) arow = N - 1;
    const float* Ap = A + (size_t)arow * DD;
    half8 af[4];
    float nsq = 0.f;
#pragma unroll
    for (int kk = 0; kk < 4; ++kk) {
      float4 x0 = *(const float4*)&Ap[kk * 32 + quad * 8];
      float4 x1 = *(const float4*)&Ap[kk * 32 + quad * 8 + 4];
      if (part)
        nsq += x0.x * x0.x + x0.y * x0.y + x0.z * x0.z + x0.w * x0.w +
               x1.x * x1.x + x1.y * x1.y + x1.z * x1.z + x1.w * x1.w;
      half8 a;
      a[0] = (_Float16)x0.x; a[1] = (_Float16)x0.y; a[2] = (_Float16)x0.z; a[3] = (_Float16)x0.w;
      a[4] = (_Float16)x1.x; a[5] = (_Float16)x1.y; a[6] = (_Float16)x1.z; a[7] = (_Float16)x1.w;
      af[kk] = a;
    }
    float fr = 1.f;
    if (part) {  // full-row norm: combine the 4 quad slices (lanes sharing m)
      nsq += __shfl_xor(nsq, 16, 64);
      nsq += __shfl_xor(nsq, 32, 64);
      float n = sqrtf(nsq);
      if (part == 1) {  // logmap0 scale
        float nc = fminf(fmaxf(n, 1e-7f), 1.0f - 1e-5f);
        fr = atanhf(nc) / fmaxf(n, 1e-7f);
      } else {          // l2norm scale
        fr = 1.0f / fmaxf(n, 1e-12f);
      }
    }
    floatx4 acc0 = {0.f, 0.f, 0.f, 0.f}, acc1 = {0.f, 0.f, 0.f, 0.f};
#pragma unroll
    for (int kk = 0; kk < 4; ++kk) {
      acc0 = __builtin_amdgcn_mfma_f32_16x16x32_f16(af[kk], bf[0][kk], acc0, 0, 0, 0);
      acc1 = __builtin_amdgcn_mfma_f32_16x16x32_f16(af[kk], bf[1][kk], acc1, 0, 0, 0);
    }
    // C/D layout: col = lane&15, row = quad*4 + reg
    int vrow = rbase + row0 + quad * 4;
#pragma unroll
    for (int reg = 0; reg < 4; ++reg) {
      int v = vrow + reg;
      float fshfl = __shfl(fr, quad * 4 + reg, 64);  // all lanes execute
      if (v < N) {
        float sc = part ? fshfl : norm_out[v];
        Qo[(size_t)v * PSTRIDE + c0 + m]      = (_Float16)(acc0[reg] * sc + bias0);
        Qo[(size_t)v * PSTRIDE + c0 + 16 + m] = (_Float16)(acc1[reg] * sc + bias1);
      }
    }
  }
}

// ---- layers >= 1 GEMM tile: A fp16 (packed P), W fp32 in-register convert ----
// part 0: out *= norm_out[row]; part 1/2: out += bias (no scales: b carries
// tangent mean directly (logmap0∘expmap0=id), s already normalized).
__device__ __forceinline__ void gemm_tile(int part, int rb, const _Float16* __restrict__ P,
                                          const float* __restrict__ Wf, const float* __restrict__ Bb,
                                          const float* __restrict__ norm_out,
                                          _Float16* __restrict__ Q, int N) {
  int t = threadIdx.x, lane = t & 63, w = t >> 6;
  int m = lane & 15, quad = lane >> 4, c0 = w * 32;
  int rbase = rb * 64;
  const _Float16* Ain = P + part * DD;
  _Float16* Qo = Q + part * DD;
  half8 bf[2][4];
#pragma unroll
  for (int tj = 0; tj < 2; ++tj)
#pragma unroll
    for (int kk = 0; kk < 4; ++kk) {
      const float* wp = &Wf[(c0 + tj * 16 + m) * DD + kk * 32 + quad * 8];
      float4 w0 = *(const float4*)wp;
      float4 w1 = *(const float4*)(wp + 4);
      half8 hv;
      hv[0] = (_Float16)w0.x; hv[1] = (_Float16)w0.y; hv[2] = (_Float16)w0.z; hv[3] = (_Float16)w0.w;
      hv[4] = (_Float16)w1.x; hv[5] = (_Float16)w1.y; hv[6] = (_Float16)w1.z; hv[7] = (_Float16)w1.w;
      bf[tj][kk] = hv;
    }
  float bias0 = 0.f, bias1 = 0.f;
  if (part) { bias0 = Bb[c0 + m]; bias1 = Bb[c0 + 16 + m]; }
#pragma unroll
  for (int r = 0; r < 4; ++r) {
    int row0 = r * 16;
    int arow = rbase + row0 + m; if (arow >= N) arow = N - 1;
    const _Float16* Ap = Ain + (size_t)arow * PSTRIDE;
    floatx4 acc0 = {0.f, 0.f, 0.f, 0.f}, acc1 = {0.f, 0.f, 0.f, 0.f};
#pragma unroll
    for (int kk = 0; kk < 4; ++kk) {
      half8 af = *(const half8*)&Ap[kk * 32 + quad * 8];
      acc0 = __builtin_amdgcn_mfma_f32_16x16x32_f16(af, bf[0][kk], acc0, 0, 0, 0);
      acc1 = __builtin_amdgcn_mfma_f32_16x16x32_f16(af, bf[1][kk], acc1, 0, 0, 0);
    }
    int vrow = rbase + row0 + quad * 4;
#pragma unroll
    for (int reg = 0; reg < 4; ++reg) {
      int v = vrow + reg;
      if (v < N) {
        float sc = part ? 1.f : norm_out[v];
        Qo[(size_t)v * PSTRIDE + c0 + m]      = (_Float16)(acc0[reg] * sc + bias0);
        Qo[(size_t)v * PSTRIDE + c0 + 16 + m] = (_Float16)(acc1[reg] * sc + bias1);
      }
    }
  }
}

// ---- K1: degree atomics (8-way bin spread, int4 edge quads, 4 RMWs in flight)
//      || layer-0 b/s GEMMs (don't need norm_out) ----
__global__ __launch_bounds__(256) void deg_gemmbs_kernel(
    const int* __restrict__ src, const int* __restrict__ dst,
    int* __restrict__ out8, int* __restrict__ in8, int* __restrict__ rank8, int E, int N,
    const float* __restrict__ b0, const float* __restrict__ s0,
    const float* __restrict__ bW, const float* __restrict__ sW,
    const float* __restrict__ bB, const float* __restrict__ sB,
    float* __restrict__ norm_out_unused, _Float16* __restrict__ Q, int DB, int GBt) {
  int bx = blockIdx.x;
  if (bx < DB) {  // degrees first (longest pole)
    int g = bx * 256 + (int)threadIdx.x;
    int e0i = g * 4;
    if (e0i + 3 < E) {
      int4 s4 = ((const int4*)src)[g];
      int4 d4 = ((const int4*)dst)[g];
      atomicAdd(&out8[((e0i    ) & 7) * N + s4.x], 1);
      atomicAdd(&out8[((e0i + 1) & 7) * N + s4.y], 1);
      atomicAdd(&out8[((e0i + 2) & 7) * N + s4.z], 1);
      atomicAdd(&out8[((e0i + 3) & 7) * N + s4.w], 1);
      int4 r;
      r.x = atomicAdd(&in8[((e0i    ) & 7) * N + d4.x], 1);
      r.y = atomicAdd(&in8[((e0i + 1) & 7) * N + d4.y], 1);
      r.z = atomicAdd(&in8[((e0i + 2) & 7) * N + d4.z], 1);
      r.w = atomicAdd(&in8[((e0i + 3) & 7) * N + d4.w], 1);
      ((int4*)rank8)[g] = r;
    } else if (e0i < E) {
      for (int e = e0i; e < E; ++e) {
        atomicAdd(&out8[(e & 7) * N + src[e]], 1);
        rank8[e] = atomicAdd(&in8[(e & 7) * N + dst[e]], 1);
      }
    }
  } else {
    int gt = bx - DB;
    int part = 1 + gt / GBt, rb = gt % GBt;
    const float* A  = (part == 1) ? b0 : s0;
    const float* Wf = (part == 1) ? bW : sW;
    const float* Bb = (part == 1) ? bB : sB;
    gemm0_tile(part, rb, A, Wf, Bb, norm_out_unused, Q, N);
  }
}

// K2: reduce 8 bins -> degrees, norms, per-block partial sums of in_deg
__global__ void norms_psum_kernel(const int* __restrict__ in8, const int* __restrict__ out8,
                                  int* __restrict__ in_deg, float* __restrict__ norm_in,
                                  float* __restrict__ norm_out, float* __restrict__ inv_in,
                                  int* __restrict__ part, int N) {
  __shared__ int wsum[4];
  int t = threadIdx.x, lane = t & 63, w = t >> 6;
  int i = blockIdx.x * 256 + t;
  int di = 0;
  if (i < N) {
    int dq = 0;
#pragma unroll
    for (int h = 0; h < 8; ++h) { di += in8[h * N + i]; dq += out8[h * N + i]; }
    in_deg[i] = di;
    norm_in[i]  = di > 0 ? 1.0f / sqrtf((float)di) : 0.0f;
    norm_out[i] = dq > 0 ? 1.0f / sqrtf((float)dq) : 0.0f;
    inv_in[i]   = di > 0 ? 1.0f / (float)di : 0.0f;
  }
  int s = wave_sum_i(di);
  if (lane == 0) wsum[w] = s;
  __syncthreads();
  if (t == 0) part[blockIdx.x] = wsum[0] + wsum[1] + wsum[2] + wsum[3];
}

__global__ void part_scan_kernel(int* __restrict__ part, int nb) {
  __shared__ int wsum[4];
  int t = threadIdx.x, lane = t & 63, w = t >> 6;
  int x = (t < nb) ? part[t] : 0;
  int v = x;
#pragma unroll
  for (int off = 1; off < 64; off <<= 1) {
    int y = __shfl_up(v, off, 64);
    if (lane >= off) v += y;
  }
  if (lane == 63) wsum[w] = v;
  __syncthreads();
  int base = 0;
  for (int j = 0; j < w; ++j) base += wsum[j];
  if (t < nb) part[t] = base + v - x;  // exclusive
}

// K4: row_off scan + convert bin counts IN PLACE to absolute CSR bin bases
__global__ void local_scan_kernel(const int* __restrict__ deg, const int* __restrict__ part,
                                  int* __restrict__ row_off, int* __restrict__ in8,
                                  int N, int E) {
  __shared__ int wsum[4];
  int t = threadIdx.x, lane = t & 63, w = t >> 6;
  int i = blockIdx.x * 256 + t;
  int x = (i < N) ? deg[i] : 0;
  int v = x;
#pragma unroll
  for (int off = 1; off < 64; off <<= 1) {
    int y = __shfl_up(v, off, 64);
    if (lane >= off) v += y;
  }
  if (lane == 63) wsum[w] = v;
  __syncthreads();
  int base = 0;
  for (int j = 0; j < w; ++j) base += wsum[j];
  if (i < N) {
    int ro = part[blockIdx.x] + base + v - x;
    row_off[i] = ro;
    int cum = ro;
#pragma unroll
    for (int h = 0; h < 8; ++h) {
      int cb = in8[h * N + i];
      in8[h * N + i] = cum;
      cum += cb;
    }
  }
  if (blockIdx.x == 0 && t == 0) row_off[N] = E;
}

// K5: atomic-free slim csr fill (4 B/edge) || layer-0 e-GEMM (needs norm_out)
__global__ __launch_bounds__(256) void fill_gemme_kernel(
    const int* __restrict__ src, const int* __restrict__ dst,
    const int* __restrict__ rank8, const int* __restrict__ bin_base,
    int* __restrict__ csr, int E,
    const float* __restrict__ e0, const float* __restrict__ eW,
    const float* __restrict__ norm_out, _Float16* __restrict__ Q, int N, int FB, int GBt) {
  int bx = blockIdx.x;
  if (bx < FB) {  // fill first (longest pole)
    int g = bx * 256 + (int)threadIdx.x;
    int e0i = g * 4;
    if (e0i + 3 < E) {
      int4 s4 = ((const int4*)src)[g];
      int4 d4 = ((const int4*)dst)[g];
      int4 r4 = ((const int4*)rank8)[g];
      csr[bin_base[((e0i    ) & 7) * N + d4.x] + r4.x] = s4.x;
      csr[bin_base[((e0i + 1) & 7) * N + d4.y] + r4.y] = s4.y;
      csr[bin_base[((e0i + 2) & 7) * N + d4.z] + r4.z] = s4.z;
      csr[bin_base[((e0i + 3) & 7) * N + d4.w] + r4.w] = s4.w;
    } else if (e0i < E) {
      for (int e = e0i; e < E; ++e)
        csr[bin_base[(e & 7) * N + dst[e]] + rank8[e]] = src[e];
    }
  } else {
    gemm0_tile(0, bx - FB, e0, eW, nullptr, norm_out, Q, N);
  }
}

// standalone GEMM for layers >= 1
__global__ __launch_bounds__(256) void gemm3_kernel(const _Float16* __restrict__ P,
                                                    const float* __restrict__ eWl,
                                                    const float* __restrict__ bWl,
                                                    const float* __restrict__ sWl,
                                                    const float* __restrict__ bBl,
                                                    const float* __restrict__ sBl,
                                                    const float* __restrict__ norm_out,
                                                    _Float16* __restrict__ Q, int N, int GBt) {
  int gt = blockIdx.x;
  int part = gt / GBt, rb = gt % GBt;
  const float* Wf = (part == 0) ? eWl : (part == 1 ? bWl : sWl);
  const float* Bb = (part == 1) ? bBl : sBl;
  gemm_tile(part, rb, P, Wf, Bb, norm_out, Q, N);
}

// Fused gather over packed Q: one wave per dst node; slim csr (src only),
// Qe pre-weighted by norm_out -> all three parts are plain sums.
// Lane = 16*g + q : group g handles neighbor slot i+g, lane loads 16B.
__global__ __launch_bounds__(256) void agg_fused_kernel(
    const _Float16* __restrict__ Q, const int* __restrict__ row_off,
    const int* __restrict__ csr, const float* __restrict__ norm_in,
    const float* __restrict__ inv_in, const float* __restrict__ eBias,
    float* __restrict__ oe, float* __restrict__ ob, float* __restrict__ os,
    _Float16* __restrict__ Pnext, int N, int write_pack, int write_out) {
  int lane = threadIdx.x & 63;
  int v = blockIdx.x * 4 + (threadIdx.x >> 6);
  if (v >= N) return;
  int g = lane >> 4, q = lane & 15;
  int beg = row_off[v], end = row_off[v + 1];
  float eacc[8], bacc[8], sacc[8];
#pragma unroll
  for (int j = 0; j < 8; ++j) { eacc[j] = 0.f; bacc[j] = 0.f; sacc[j] = 0.f; }
  int i = beg;
  for (; i + 8 <= end; i += 8) {  // 8 neighbors/iter, 6 x 16B gathers in flight
    int na = csr[i + g], nb2 = csr[i + 4 + g];
    const _Float16* ra = Q + (size_t)na * PSTRIDE + q * 8;
    const _Float16* rb = Q + (size_t)nb2 * PSTRIDE + q * 8;
    half8 ea = *(const half8*)ra;
    half8 e2 = *(const half8*)rb;
    half8 ba = *(const half8*)(ra + 128);
    half8 b2 = *(const half8*)(rb + 128);
    half8 sa = *(const half8*)(ra + 256);
    half8 s2 = *(const half8*)(rb + 256);
#pragma unroll
    for (int j = 0; j < 8; ++j) {
      eacc[j] += (float)ea[j]; eacc[j] += (float)e2[j];
      bacc[j] += (float)ba[j]; bacc[j] += (float)b2[j];
      sacc[j] += (float)sa[j]; sacc[j] += (float)s2[j];
    }
  }
  if (i + 4 <= end) {
    int na = csr[i + g];
    const _Float16* rp = Q + (size_t)na * PSTRIDE + q * 8;
    half8 ev = *(const half8*)rp;
    half8 bv = *(const half8*)(rp + 128);
    half8 sv = *(const half8*)(rp + 256);
#pragma unroll
    for (int j = 0; j < 8; ++j) {
      eacc[j] += (float)ev[j];
      bacc[j] += (float)bv[j];
      sacc[j] += (float)sv[j];
    }
    i += 4;
  }
  if (i + g < end) {
    int na = csr[i + g];
    const _Float16* rp = Q + (size_t)na * PSTRIDE + q * 8;
    half8 ev = *(const half8*)rp;
    half8 bv = *(const half8*)(rp + 128);
    half8 sv = *(const half8*)(rp + 256);
#pragma unroll
    for (int j = 0; j < 8; ++j) {
      eacc[j] += (float)ev[j];
      bacc[j] += (float)bv[j];
      sacc[j] += (float)sv[j];
    }
  }
#pragma unroll
  for (int j = 0; j < 8; ++j) {  // combine the 4 neighbor-groups
    eacc[j] += __shfl_xor(eacc[j], 16, 64);
    eacc[j] += __shfl_xor(eacc[j], 32, 64);
    bacc[j] += __shfl_xor(bacc[j], 16, 64);
    bacc[j] += __shfl_xor(bacc[j], 32, 64);
    sacc[j] += __shfl_xor(sacc[j], 16, 64);
    sacc[j] += __shfl_xor(sacc[j], 32, 64);
  }
  float ni = norm_in[v], iv = inv_in[v];
  const float4* ebp = (const float4*)eBias;
  float4 eb0 = ebp[q * 2], eb1 = ebp[q * 2 + 1];
  float bias[8] = {eb0.x, eb0.y, eb0.z, eb0.w, eb1.x, eb1.y, eb1.z, eb1.w};
  float h[8], ub[8], us[8];
  float ss2 = 0.f;
#pragma unroll
  for (int j = 0; j < 8; ++j) {
    float tt = eacc[j] * ni + bias[j];
    h[j] = tt > 0.f ? tt : 0.2f * tt;
    ub[j] = bacc[j] * iv;                 // tangent mean (b)
    us[j] = sacc[j] * iv; ss2 += us[j] * us[j];
  }
  float ns = sqrtf(g16_sum(ss2));
  float fs = 1.0f / fmaxf(ns, 1e-12f);    // l2norm scale
  if (write_out) {  // final layer: fp32 outputs, split across lane-groups
    float bs2 = 0.f;
#pragma unroll
    for (int j = 0; j < 8; ++j) bs2 += ub[j] * ub[j];
    float nb = sqrtf(g16_sum(bs2));
    float fb = tanhf(nb) / fmaxf(nb, 1e-7f);  // expmap0
    if (g == 0) {
      float4* p = (float4*)(oe + (size_t)v * DD);
      p[q * 2]     = make_float4(h[0], h[1], h[2], h[3]);
      p[q * 2 + 1] = make_float4(h[4], h[5], h[6], h[7]);
    } else if (g == 1) {
      float4* p = (float4*)(ob + (size_t)v * DD);
      p[q * 2]     = make_float4(ub[0] * fb, ub[1] * fb, ub[2] * fb, ub[3] * fb);
      p[q * 2 + 1] = make_float4(ub[4] * fb, ub[5] * fb, ub[6] * fb, ub[7] * fb);
    } else if (g == 2) {
      float4* p = (float4*)(os + (size_t)v * DD);
      p[q * 2]     = make_float4(us[0] * fs, us[1] * fs, us[2] * fs, us[3] * fs);
      p[q * 2 + 1] = make_float4(us[4] * fs, us[5] * fs, us[6] * fs, us[7] * fs);
    }
  }
  if (write_pack && g == 3) {  // non-final layers: fp16 pack only
    half8 he, hb, hs;
#pragma unroll
    for (int j = 0; j < 8; ++j) {
      he[j] = (_Float16)h[j];
      hb[j] = (_Float16)ub[j];
      hs[j] = (_Float16)(us[j] * fs);
    }
    _Float16* Pr = Pnext + (size_t)v * PSTRIDE + q * 8;
    *(half8*)&Pr[0]   = he;
    *(half8*)&Pr[128] = hb;
    *(half8*)&Pr[256] = hs;
  }
}

extern "C" void kernel_launch(void* const* d_in, const int* in_sizes, int n_in,
                              void* d_out, int out_size, void* d_ws, size_t ws_size,
                              hipStream_t stream) {
  const float* e0 = (const float*)d_in[0];
  const float* b0 = (const float*)d_in[1];
  const float* s0 = (const float*)d_in[2];
  const float* eW = (const float*)d_in[3];
  const float* eB = (const float*)d_in[4];
  const float* bW = (const float*)d_in[5];
  const float* bB = (const float*)d_in[6];
  const float* sW = (const float*)d_in[7];
  const float* sB = (const float*)d_in[8];
  const int* src = (const int*)d_in[9];
  const int* dst = (const int*)d_in[10];
  int N = in_sizes[0] / DD;
  int E = in_sizes[9];
  int L = in_sizes[3] / (DD * DD);

  char* w = (char*)d_ws;
  // [in_deg8 | out_deg8] contiguous -> single memset
  int* in_deg8  = (int*)w; w += (size_t)8 * N * 4;  // becomes absolute bin bases
  int* out_deg8 = (int*)w; w += (size_t)8 * N * 4;
  int* rank8    = (int*)w; w += (size_t)E * 4;
  int* in_deg   = (int*)w; w += (size_t)N * 4;
  int* row_off  = (int*)w; w += (size_t)(N + 4) * 4;
  int* pscan    = (int*)w; w += (size_t)1024 * 4;
  int* csr      = (int*)w; w += (size_t)E * 4;
  float* norm_in  = (float*)w; w += (size_t)N * 4;
  float* norm_out = (float*)w; w += (size_t)N * 4;
  float* inv_in   = (float*)w; w += (size_t)N * 4;
  w = (char*)(((size_t)w + 255) & ~(size_t)255);  // align
  _Float16* P = (_Float16*)w; w += (size_t)N * PSTRIDE * 2;
  _Float16* Q = (_Float16*)w; w += (size_t)N * PSTRIDE * 2;

  float* oe = (float*)d_out;
  float* ob = oe + (size_t)N * DD;
  float* os = ob + (size_t)N * DD;

  int DB  = (E + 1023) / 1024;  // 4 edges/thread
  int ABt = (N + 3) / 4;
  int GBt = (N + 63) / 64;
  int NC  = (N + 255) / 256;

  hipMemsetAsync(d_ws, 0, (size_t)16 * N * 4, stream);  // degree bins
  deg_gemmbs_kernel<<<DB + 2 * GBt, 256, 0, stream>>>(src, dst, out_deg8, in_deg8, rank8, E, N,
                                                      b0, s0, bW, sW, bB, sB, norm_out, Q, DB, GBt);
  norms_psum_kernel<<<NC, 256, 0, stream>>>(in_deg8, out_deg8, in_deg,
                                            norm_in, norm_out, inv_in, pscan, N);
  part_scan_kernel<<<1, 256, 0, stream>>>(pscan, NC);
  local_scan_kernel<<<NC, 256, 0, stream>>>(in_deg, pscan, row_off, in_deg8, N, E);
  fill_gemme_kernel<<<DB + GBt, 256, 0, stream>>>(src, dst, rank8, in_deg8, csr, E,
                                                  e0, eW, norm_out, Q, N, DB, GBt);
  agg_fused_kernel<<<ABt, 256, 0, stream>>>(Q, row_off, csr, norm_in, inv_in, eB,
                                            oe, ob, os, P, N,
                                            (L > 1) ? 1 : 0, (L == 1) ? 1 : 0);
  for (int l = 1; l < L; ++l) {
    size_t lo = (size_t)l * DD * DD;
    gemm3_kernel<<<3 * GBt, 256, 0, stream>>>(P, eW + lo, bW + lo, sW + lo,
                                              bB + (size_t)l * DD, sB + (size_t)l * DD,
                                              norm_out, Q, N, GBt);
    agg_fused_kernel<<<ABt, 256, 0, stream>>>(Q, row_off, csr, norm_in, inv_in,
                                              eB + (size_t)l * DD, oe, ob, os, P, N,
                                              (l < L - 1) ? 1 : 0, (l == L - 1) ? 1 : 0);
  }
}